// Round 1
// 1063.102 us; speedup vs baseline: 1.1235x; 1.1235x over previous
//
#include <hip/hip_runtime.h>
#include <hip/hip_bf16.h>

// EquivariantInteractionBlock on MI355X (gfx950).
// R5: de-latency the edge kernel.
//  - Segmented reduce: 256 threads (2 halves x 2 streams x 64 ch-pairs),
//    8-wide batched LDS reads, ballot-derived cut mask in SGPRs (scalar
//    branch), ids[] read only at boundaries. Was: 128 threads x 64-deep
//    serial LDS-latency chain (~8K cy/tile).
//  - Gather software pipeline: next tile's perm/edge_j/edge_i issued under
//    GEMM; h/edge_feat/sh loads (packed to bf16 in regs) issued under the
//    reduce. Stage phase is pure reg->LDS writes.
//  - Grid 512 = exactly 2 resident blocks/CU, persistent tiles.

#define Hdim 128
#define Fdim 64
#define Mdim 16
#define TE   64    // edges (or nodes) per block tile
#define XLD  200   // LDS leading dim for [64][192] tile (16B-aligned rows)
#define YLD  132   // LDS leading dim for [64][128] tiles (8B-aligned rows)
#define SLD  40    // LDS leading dim for sh [64][32] tile

typedef __attribute__((ext_vector_type(8))) short short8;
typedef __attribute__((ext_vector_type(4))) short short4v;
typedef __attribute__((ext_vector_type(4))) float float4v;

__device__ __forceinline__ float b2f(short s) {
    union { unsigned u; float f; } c;
    c.u = ((unsigned)(unsigned short)s) << 16;
    return c.f;
}
__device__ __forceinline__ short f2b(float f) {
    union { __hip_bfloat16 h; short s; } c;
    c.h = __float2bfloat16(f);
    return c.s;
}
__device__ __forceinline__ float ldf(const void* p, long i, int isbf) {
    return isbf ? b2f(((const short*)p)[i]) : ((const float*)p)[i];
}
__device__ __forceinline__ int ldi(const void* p, long i, int is64) {
    return is64 ? (int)((const long long*)p)[i] : ((const int*)p)[i];
}
__device__ __forceinline__ short8 pack8(const float4v a, const float4v b) {
    short8 t;
#pragma unroll
    for (int r = 0; r < 4; ++r) { t[r] = f2b(a[r]); t[4 + r] = f2b(b[r]); }
    return t;
}

// flags[0] = 1 if float tensors are bf16, 0 if f32
// flags[1] = 1 if index tensors are int64, 0 if int32
__global__ void ei_sniff_kernel(const unsigned* __restrict__ hw,
                                const unsigned* __restrict__ iw,
                                int* __restrict__ flags)
{
    __shared__ int cf[64], ci[64];
    const int t = threadIdx.x;
    int c1 = 0, c2 = 0;
#pragma unroll
    for (int k = 0; k < 4; ++k) {
        const unsigned w = hw[t + 64 * k];
        const unsigned e = (w >> 7) & 0xFFu;
        c1 += (e >= 100u && e <= 140u) ? 1 : 0;
        const unsigned wi = iw[2 * (t + 64 * k) + 1];
        c2 += (wi == 0u) ? 1 : 0;
    }
    cf[t] = c1; ci[t] = c2;
    __syncthreads();
    if (t == 0) {
        int s1 = 0, s2 = 0;
        for (int i = 0; i < 64; ++i) { s1 += cf[i]; s2 += ci[i]; }
        flags[0] = (s1 >= 192) ? 1 : 0;
        flags[1] = (s2 >= 200) ? 1 : 0;
    }
}

// ---------------- sort path: hist -> scan -> scatter ----------------

__global__ void ei_hist_kernel(const void* __restrict__ edge_i,
                               int* __restrict__ hist,
                               const int* __restrict__ flags, int E_)
{
    const int dti = flags[1];
    int i = blockIdx.x * blockDim.x + threadIdx.x;
    const int stride = gridDim.x * blockDim.x;
    for (; i < E_; i += stride) atomicAdd(&hist[ldi(edge_i, i, dti)], 1);
}

// 1 block, 1024 threads. hist doubles as cursor output (row starts).
__global__ void ei_scan_kernel(int* __restrict__ hist,
                               int* __restrict__ rs, int N_, int E_)
{
    __shared__ int buf[1024];
    const int t = threadIdx.x;
    const int chunk = (N_ + 1023) >> 10;
    const int base = t * chunk;
    int s = 0;
    for (int i = 0; i < chunk; ++i) {
        const int idx = base + i;
        if (idx < N_) s += hist[idx];
    }
    buf[t] = s;
    __syncthreads();
    for (int d = 1; d < 1024; d <<= 1) {
        const int v = (t >= d) ? buf[t - d] : 0;
        __syncthreads();
        buf[t] += v;
        __syncthreads();
    }
    int run = buf[t] - s;   // exclusive prefix
    for (int i = 0; i < chunk; ++i) {
        const int idx = base + i;
        if (idx >= N_) break;
        const int h = hist[idx];
        rs[idx] = run;
        hist[idx] = run;    // becomes scatter cursor
        run += h;
    }
    if (t == 0) rs[N_] = E_;
}

__global__ void ei_scatter_kernel(const void* __restrict__ edge_i,
                                  int* __restrict__ cur,
                                  int* __restrict__ perm,
                                  const int* __restrict__ flags, int E_)
{
    const int dti = flags[1];
    int i = blockIdx.x * blockDim.x + threadIdx.x;
    const int stride = gridDim.x * blockDim.x;
    for (; i < E_; i += stride) {
        const int c = ldi(edge_i, i, dti);
        const int p = atomicAdd(&cur[c], 1);
        perm[p] = i;
    }
}

// ---------------- W2up = W2 @ W_up (bf16), bu2 = b2 @ W_up (f32) ------------
__global__ void ei_w2up_kernel(const void* __restrict__ W2,
                               const void* __restrict__ Wup,
                               const void* __restrict__ b2,
                               short* __restrict__ w2up,
                               float* __restrict__ bu2,
                               const int* __restrict__ flags)
{
    const int dtf = flags[0];
    const int o = threadIdx.x;   // 0..127
    const int i = blockIdx.x;    // 0..128 (128 = bias row)
    float acc = 0.f;
    for (int m = 0; m < Hdim; ++m) {
        const float a = (i < Hdim) ? ldf(W2, (long)i * Hdim + m, dtf)
                                   : ldf(b2, m, dtf);
        acc += a * ldf(Wup, (long)m * Hdim + o, dtf);
    }
    if (i < Hdim) w2up[i * Hdim + o] = f2b(acc);
    else          bu2[o] = acc;
}

// ---------------- sorted edge kernel with in-tile segmented reduce ----------
//   Y  = silu([h_j|edge_feat] @ W1 + b1)                 -> segsum -> agg_y
//   eq = (h_j @ W_in + b_in) * (sh @ W_tp)               -> segsum -> agg_q
__global__ __launch_bounds__(256, 2)
void ei_edge_sorted(const void* __restrict__ hmat,
                    const void* __restrict__ efeat,
                    const void* __restrict__ shmat,
                    const void* __restrict__ edge_j,
                    const int*  __restrict__ perm,
                    const int*  __restrict__ edge_i_sorted_src, // raw edge_i
                    const void* __restrict__ W1,
                    const void* __restrict__ b1,
                    const void* __restrict__ Win,
                    const void* __restrict__ bin,
                    const void* __restrict__ Wtp,
                    float* __restrict__ agg_y,
                    float* __restrict__ agg_q,
                    const int* __restrict__ flags,
                    int ntiles)
{
    __shared__ alignas(16) short Xs[TE][XLD];  // [edge][k] ([h_j | edge_feat])
    __shared__ alignas(16) short Ys[TE][YLD];  // silu output (bf16)
    __shared__ alignas(16) short Qs[TE][YLD];  // eq msg (bf16)
    __shared__ alignas(16) short Ss[TE][SLD];  // sh [0..15], zeros [16..31]
    __shared__ int ids[TE];                    // sorted destination ids

    const int dtf = flags[0];
    const int dti = flags[1];

    const int tid  = threadIdx.x;
    const int lane = tid & 63;
    const int wv   = tid >> 6;
    const int q    = lane >> 4;
    const int ln   = lane & 15;
    const int mch0 = wv * 32;

    // one-time zero (covers pads; Ss[16..31] must stay zero)
    for (int i = tid; i < TE * XLD; i += 256) ((short*)Xs)[i] = 0;
    for (int i = tid; i < TE * YLD; i += 256) ((short*)Ys)[i] = 0;
    for (int i = tid; i < TE * YLD; i += 256) ((short*)Qs)[i] = 0;
    for (int i = tid; i < TE * SLD; i += 256) ((short*)Ss)[i] = 0;
    __syncthreads();

    // persistent weight A-fragments (lane m = out-channel, k contiguous-8)
    short8 w1f[6][2], wif[4][2], wtf[2];
    float4v b1v[2], biv[2];
#pragma unroll
    for (int mt = 0; mt < 2; ++mt) {
        const int m = mch0 + mt * 16 + ln;
#pragma unroll
        for (int kc = 0; kc < 6; ++kc) {
            short8 t;
            const int k0 = kc * 32 + q * 8;
#pragma unroll
            for (int j = 0; j < 8; ++j) t[j] = dtf ? ((const short*)W1)[(long)(k0 + j) * Hdim + m]
                                                   : f2b(((const float*)W1)[(long)(k0 + j) * Hdim + m]);
            w1f[kc][mt] = t;
        }
#pragma unroll
        for (int kc = 0; kc < 4; ++kc) {
            short8 u;
            const int k0 = kc * 32 + q * 8;
#pragma unroll
            for (int j = 0; j < 8; ++j) {
                const long idx = (long)(k0 + j) * Hdim + m;
                u[j] = dtf ? ((const short*)Win)[idx] : f2b(((const float*)Win)[idx]);
            }
            wif[kc][mt] = u;
        }
        {
            short8 t;
#pragma unroll
            for (int j = 0; j < 8; ++j) {
                const int k = q * 8 + j;
                t[j] = (k < Mdim) ? (dtf ? ((const short*)Wtp)[(long)k * Hdim + m]
                                         : f2b(((const float*)Wtp)[(long)k * Hdim + m]))
                                  : (short)0;
            }
            wtf[mt] = t;
        }
        const int cb = mch0 + mt * 16 + q * 4;
#pragma unroll
        for (int r = 0; r < 4; ++r) {
            b1v[mt][r] = ldf(b1, cb + r, dtf);
            biv[mt][r] = ldf(bin, cb + r, dtf);
        }
    }

    const int e_loc = tid >> 2;
    const int part  = tid & 3;

    // ---- software-pipeline registers (always bf16 LDS-image) ----
    short8 xh[4];   // 32 shorts of h_j row     -> Xs[e_loc][part*32 ..]
    short8 xf[2];   // 16 shorts of edge_feat   -> Xs[e_loc][128+part*16 ..]
    short8 xs2[2];  // 16 shorts of sh (part 0) -> Ss[e_loc][0..15]
    int nx_e = 0, nx_j = 0, nx_pid = 0;

    // prefetch A: indices for tile t (perm -> edge_j / edge_i chain)
    auto prefA = [&](int t) {
        const int base = t * TE;
        nx_e = perm[base + e_loc];
        nx_j = ldi(edge_j, nx_e, dti);
        if (tid < TE) nx_pid = ldi(edge_i_sorted_src, perm[base + tid], dti);
    };
    // prefetch B: payload for tile t (uses nx_e / nx_j), packed to bf16
    auto prefB = [&]() {
        if (dtf) {
            const short8* hs = (const short8*)((const short*)hmat + (long)nx_j * Hdim);
#pragma unroll
            for (int c = 0; c < 4; ++c) xh[c] = hs[part * 4 + c];
            const short8* fs = (const short8*)((const short*)efeat + (long)nx_e * Fdim);
            xf[0] = fs[part * 2 + 0];
            xf[1] = fs[part * 2 + 1];
            if (part == 0) {
                const short8* ss = (const short8*)((const short*)shmat + (long)nx_e * Mdim);
                xs2[0] = ss[0];
                xs2[1] = ss[1];
            }
        } else {
            const float4v* hs = (const float4v*)((const float*)hmat + (long)nx_j * Hdim + part * 32);
#pragma unroll
            for (int c = 0; c < 4; ++c) xh[c] = pack8(hs[2 * c], hs[2 * c + 1]);
            const float4v* fs = (const float4v*)((const float*)efeat + (long)nx_e * Fdim + part * 16);
            xf[0] = pack8(fs[0], fs[1]);
            xf[1] = pack8(fs[2], fs[3]);
            if (part == 0) {
                const float4v* ss = (const float4v*)((const float*)shmat + (long)nx_e * Mdim);
                xs2[0] = pack8(ss[0], ss[1]);
                xs2[1] = pack8(ss[2], ss[3]);
            }
        }
    };

    int tile = blockIdx.x;
    if (tile < ntiles) { prefA(tile); prefB(); }

    for (; tile < ntiles; tile += gridDim.x) {
        // ---- stage: pure reg -> LDS writes ----
#pragma unroll
        for (int c = 0; c < 4; ++c)
            *(short8*)&Xs[e_loc][part * 32 + c * 8] = xh[c];
        *(short8*)&Xs[e_loc][Hdim + part * 16]     = xf[0];
        *(short8*)&Xs[e_loc][Hdim + part * 16 + 8] = xf[1];
        if (part == 0) {
            *(short8*)&Ss[e_loc][0] = xs2[0];
            *(short8*)&Ss[e_loc][8] = xs2[1];
        }
        if (tid < TE) ids[tid] = nx_pid;
        __syncthreads();

        // cut mask: bit e set iff run ends at edge e (uniform, lives in SGPRs)
        const unsigned long long bmask =
            __ballot((lane == 63) || (ids[lane + 1] != ids[lane]));

        // issue next tile's index chain now (hides under the GEMMs)
        int nxt = tile + (int)gridDim.x;
        if (nxt >= ntiles) nxt = tile;   // clamp: valid loads, results unused
        prefA(nxt);

        // ---- GEMM1: Y = silu(X @ W1 + b1), K = 192 -> Ys ----
        float4v a1[2][4] = {};
#pragma unroll
        for (int kc = 0; kc < 6; ++kc) {
            short8 xb[4];
#pragma unroll
            for (int nt = 0; nt < 4; ++nt)
                xb[nt] = *(const short8*)&Xs[nt * 16 + ln][kc * 32 + q * 8];
#pragma unroll
            for (int nt = 0; nt < 4; ++nt)
#pragma unroll
                for (int mt = 0; mt < 2; ++mt)
                    a1[mt][nt] = __builtin_amdgcn_mfma_f32_16x16x32_bf16(
                        w1f[kc][mt], xb[nt], a1[mt][nt], 0, 0, 0);
        }
#pragma unroll
        for (int mt = 0; mt < 2; ++mt)
#pragma unroll
            for (int nt = 0; nt < 4; ++nt) {
                short4v p;
#pragma unroll
                for (int r = 0; r < 4; ++r) {
                    const float y = a1[mt][nt][r] + b1v[mt][r];
                    const float s = y / (1.f + __expf(-y));
                    p[r] = f2b(s);
                }
                *(short4v*)&Ys[nt * 16 + ln][mch0 + mt * 16 + q * 4] = p;
            }

        // ---- GEMM3: eq = (h_j @ W_in + b_in) * (sh @ W_tp) -> Qs ----
        float4v a3[2][4] = {};
        float4v at[2][4] = {};
#pragma unroll
        for (int kc = 0; kc < 4; ++kc) {
            short8 xb[4];
#pragma unroll
            for (int nt = 0; nt < 4; ++nt)
                xb[nt] = *(const short8*)&Xs[nt * 16 + ln][kc * 32 + q * 8];
#pragma unroll
            for (int nt = 0; nt < 4; ++nt)
#pragma unroll
                for (int mt = 0; mt < 2; ++mt)
                    a3[mt][nt] = __builtin_amdgcn_mfma_f32_16x16x32_bf16(
                        wif[kc][mt], xb[nt], a3[mt][nt], 0, 0, 0);
        }
        {
            short8 sb[4];
#pragma unroll
            for (int nt = 0; nt < 4; ++nt)
                sb[nt] = *(const short8*)&Ss[nt * 16 + ln][q * 8];
#pragma unroll
            for (int nt = 0; nt < 4; ++nt)
#pragma unroll
                for (int mt = 0; mt < 2; ++mt)
                    at[mt][nt] = __builtin_amdgcn_mfma_f32_16x16x32_bf16(
                        wtf[mt], sb[nt], at[mt][nt], 0, 0, 0);
        }
#pragma unroll
        for (int mt = 0; mt < 2; ++mt)
#pragma unroll
            for (int nt = 0; nt < 4; ++nt) {
                short4v p;
#pragma unroll
                for (int r = 0; r < 4; ++r)
                    p[r] = f2b((a3[mt][nt][r] + biv[mt][r]) * at[mt][nt][r]);
                *(short4v*)&Qs[nt * 16 + ln][mch0 + mt * 16 + q * 4] = p;
            }

        // issue next tile's payload loads now (latency hides under reduce)
        prefB();
        __syncthreads();

        // ---- segmented reduce: 256 threads, 2 halves x 2 streams ----
        // half boundary is treated like a tile boundary (atomic); interior
        // runs are exclusive-writer plain stores.
        {
            const int half = tid >> 7;
            const int qsel = (tid >> 6) & 1;
            const int c2   = tid & 63;
            const short* srcb = qsel ? &Qs[0][0] : &Ys[0][0];
            float* agg = qsel ? agg_q : agg_y;
            const int e0 = half * 32;
            float v0 = 0.f, v1 = 0.f;
            int run_start = e0;
#pragma unroll
            for (int eb = 0; eb < 4; ++eb) {
                unsigned wb[8];
#pragma unroll
                for (int k = 0; k < 8; ++k)
                    wb[k] = *(const unsigned*)(srcb + (e0 + eb * 8 + k) * YLD + 2 * c2);
#pragma unroll
                for (int k = 0; k < 8; ++k) {
                    const int e = e0 + eb * 8 + k;
                    union { unsigned u; float f; } lo, hi;
                    lo.u = wb[k] << 16;
                    hi.u = wb[k] & 0xFFFF0000u;
                    v0 += lo.f;
                    v1 += hi.f;
                    const bool hend = (e == e0 + 31);
                    if (hend || ((bmask >> e) & 1ull)) {
                        const int id = ids[e];
                        float* dst = agg + (long)id * Hdim + 2 * c2;
                        if (hend || run_start == e0) {
                            // run may continue in the other half / adjacent tile
                            unsafeAtomicAdd(dst, v0);
                            unsafeAtomicAdd(dst + 1, v1);
                        } else {
                            float2 st; st.x = v0; st.y = v1;
                            *(float2*)dst = st;
                        }
                        v0 = 0.f; v1 = 0.f;
                        run_start = e + 1;
                    }
                }
            }
        }
        __syncthreads();
    }
}

// ---------------- node kernel ----------------
// h_new    = h + bf16(agg_y) @ W2up + deg*bu2 + b_up
// gate     = sigmoid(h_new @ W_gate + b_gate)
// h_eq_new = h_eq + agg_q * gate
__global__ __launch_bounds__(256, 2)
void ei_node_kernel(const void* __restrict__ hmat,
                    const void* __restrict__ heq,
                    const short* __restrict__ w2up,
                    const float* __restrict__ bu2,
                    const void* __restrict__ bup,
                    const void* __restrict__ Wg,
                    const void* __restrict__ bg,
                    const int*  __restrict__ rs,
                    const float* __restrict__ agg_y,
                    const float* __restrict__ agg_q,
                    void* __restrict__ outp,
                    const int* __restrict__ flags,
                    int N)
{
    __shared__ alignas(16) short Xa[TE][YLD];  // bf16(agg_y) tile
    __shared__ alignas(16) short Yh[TE][YLD];  // bf16(h_new) tile
    __shared__ int degs[TE];

    const int dtf = flags[0];

    const int tid  = threadIdx.x;
    const int lane = tid & 63;
    const int wv   = tid >> 6;
    const int q    = lane >> 4;
    const int ln   = lane & 15;
    const int mch0 = wv * 32;

    short* outh_b = (short*)outp;
    short* outq_b = outh_b + (long)N * Hdim;
    float* outh_f = (float*)outp;
    float* outq_f = outh_f + (long)N * Hdim;

    short8 wcf[4][2], wgf[4][2];
    float4v bu2v[2], bupv[2], bgv[2];
#pragma unroll
    for (int mt = 0; mt < 2; ++mt) {
        const int m = mch0 + mt * 16 + ln;
#pragma unroll
        for (int kc = 0; kc < 4; ++kc) {
            short8 t, u;
            const int k0 = kc * 32 + q * 8;
#pragma unroll
            for (int j = 0; j < 8; ++j) {
                const long idx = (long)(k0 + j) * Hdim + m;
                t[j] = w2up[idx];   // ws, always bf16
                u[j] = dtf ? ((const short*)Wg)[idx] : f2b(((const float*)Wg)[idx]);
            }
            wcf[kc][mt] = t;
            wgf[kc][mt] = u;
        }
        const int cb = mch0 + mt * 16 + q * 4;
#pragma unroll
        for (int r = 0; r < 4; ++r) {
            bu2v[mt][r] = bu2[cb + r];
            bupv[mt][r] = ldf(bup, cb + r, dtf);
            bgv[mt][r]  = ldf(bg, cb + r, dtf);
        }
    }

    const int e_loc = tid >> 2;
    const int part  = tid & 3;
    const int nb    = blockIdx.x * TE;

    // stage bf16(agg_y) tile + degrees
    {
        const int node = nb + e_loc;
        if (node < N) {
            const float4v* src = (const float4v*)(agg_y + (long)node * Hdim + part * 32);
#pragma unroll
            for (int c = 0; c < 4; ++c) {
                const float4v v0 = src[2 * c], v1 = src[2 * c + 1];
                short8 t;
#pragma unroll
                for (int r = 0; r < 4; ++r) { t[r] = f2b(v0[r]); t[4 + r] = f2b(v1[r]); }
                *(short8*)&Xa[e_loc][part * 32 + c * 8] = t;
            }
            if (part == 0) degs[e_loc] = rs[node + 1] - rs[node];
        } else {
            short8 z = {};
#pragma unroll
            for (int c = 0; c < 4; ++c)
                *(short8*)&Xa[e_loc][part * 32 + c * 8] = z;
            if (part == 0) degs[e_loc] = 0;
        }
    }
    __syncthreads();

    // GEMM: agg_y @ W2up ; h_new epilogue
    float4v au[2][4] = {};
#pragma unroll
    for (int kc = 0; kc < 4; ++kc) {
        short8 ab[4];
#pragma unroll
        for (int nt = 0; nt < 4; ++nt)
            ab[nt] = *(const short8*)&Xa[nt * 16 + ln][kc * 32 + q * 8];
#pragma unroll
        for (int nt = 0; nt < 4; ++nt)
#pragma unroll
            for (int mt = 0; mt < 2; ++mt)
                au[mt][nt] = __builtin_amdgcn_mfma_f32_16x16x32_bf16(
                    wcf[kc][mt], ab[nt], au[mt][nt], 0, 0, 0);
    }
#pragma unroll
    for (int mt = 0; mt < 2; ++mt)
#pragma unroll
        for (int nt = 0; nt < 4; ++nt) {
            const int nd = nb + nt * 16 + ln;
            const int ch = mch0 + mt * 16 + q * 4;
            short4v p;
            if (nd < N) {
                const float dg = (float)degs[nt * 16 + ln];
                float hv[4];
                if (dtf) {
                    const short4v x = *(const short4v*)((const short*)hmat + (long)nd * Hdim + ch);
#pragma unroll
                    for (int r = 0; r < 4; ++r) hv[r] = b2f(x[r]);
                } else {
                    const float4v x = *(const float4v*)((const float*)hmat + (long)nd * Hdim + ch);
#pragma unroll
                    for (int r = 0; r < 4; ++r) hv[r] = x[r];
                }
                float4v o;
#pragma unroll
                for (int r = 0; r < 4; ++r) {
                    o[r] = hv[r] + au[mt][nt][r] + dg * bu2v[mt][r] + bupv[mt][r];
                    p[r] = f2b(o[r]);
                }
                if (dtf) *(short4v*)(outh_b + (long)nd * Hdim + ch) = p;
                else     *(float4v*)(outh_f + (long)nd * Hdim + ch) = o;
            } else {
#pragma unroll
                for (int r = 0; r < 4; ++r) p[r] = 0;
            }
            *(short4v*)&Yh[nt * 16 + ln][ch] = p;
        }
    __syncthreads();

    // GEMM: h_new @ W_gate ; h_eq_new epilogue
    float4v ag[2][4] = {};
#pragma unroll
    for (int kc = 0; kc < 4; ++kc) {
        short8 yb[4];
#pragma unroll
        for (int nt = 0; nt < 4; ++nt)
            yb[nt] = *(const short8*)&Yh[nt * 16 + ln][kc * 32 + q * 8];
#pragma unroll
        for (int nt = 0; nt < 4; ++nt)
#pragma unroll
            for (int mt = 0; mt < 2; ++mt)
                ag[mt][nt] = __builtin_amdgcn_mfma_f32_16x16x32_bf16(
                    wgf[kc][mt], yb[nt], ag[mt][nt], 0, 0, 0);
    }
#pragma unroll
    for (int mt = 0; mt < 2; ++mt)
#pragma unroll
        for (int nt = 0; nt < 4; ++nt) {
            const int nd = nb + nt * 16 + ln;
            if (nd >= N) continue;
            const int ch = mch0 + mt * 16 + q * 4;
            const float4v aq = *(const float4v*)(agg_q + (long)nd * Hdim + ch);
            float hev[4];
            if (dtf) {
                const short4v x = *(const short4v*)((const short*)heq + (long)nd * Hdim + ch);
#pragma unroll
                for (int r = 0; r < 4; ++r) hev[r] = b2f(x[r]);
            } else {
                const float4v x = *(const float4v*)((const float*)heq + (long)nd * Hdim + ch);
#pragma unroll
                for (int r = 0; r < 4; ++r) hev[r] = x[r];
            }
            short4v p;
            float4v o;
#pragma unroll
            for (int r = 0; r < 4; ++r) {
                const float g = 1.f / (1.f + __expf(-(ag[mt][nt][r] + bgv[mt][r])));
                o[r] = hev[r] + aq[r] * g;
                p[r] = f2b(o[r]);
            }
            if (dtf) *(short4v*)(outq_b + (long)nd * Hdim + ch) = p;
            else     *(float4v*)(outq_f + (long)nd * Hdim + ch) = o;
        }
}

extern "C" void kernel_launch(void* const* d_in, const int* in_sizes, int n_in,
                              void* d_out, int out_size, void* d_ws, size_t ws_size,
                              hipStream_t stream)
{
    (void)n_in; (void)out_size; (void)ws_size;
    const void* hmat  = d_in[0];
    const void* heq   = d_in[1];
    const void* efeat = d_in[2];
    const void* shm   = d_in[3];
    const void* ei    = d_in[4];
    const void* ej    = d_in[5];
    const void* Win   = d_in[6];
    const void* bin   = d_in[7];
    const void* Wg    = d_in[8];
    const void* bg    = d_in[9];
    const void* W1    = d_in[10];
    const void* b1    = d_in[11];
    const void* W2    = d_in[12];
    const void* b2    = d_in[13];
    const void* Wup   = d_in[14];
    const void* bup   = d_in[15];
    const void* Wtp   = d_in[16];

    const int N = in_sizes[0] / Hdim;
    const int E = in_sizes[2] / Fdim;

    // ws layout (~56 MB)
    auto al = [](size_t x) { return (x + 255) & ~(size_t)255; };
    size_t off = 8;                                   // flags
    off = al(off); const size_t rs_off   = off; off += (size_t)(N + 1) * 4;
    off = al(off); const size_t cur_off  = off; off += (size_t)N * 4;
    off = al(off); const size_t perm_off = off; off += (size_t)E * 4;
    off = al(off); const size_t aggy_off = off; off += (size_t)N * Hdim * 4;
    const size_t aggq_off = off;                     off += (size_t)N * Hdim * 4;
    off = al(off); const size_t w2_off   = off; off += (size_t)Hdim * Hdim * 2;
    off = al(off); const size_t bu2_off  = off; off += (size_t)Hdim * 4;

    char* w = (char*)d_ws;
    int*   flags = (int*)w;
    int*   rs    = (int*)(w + rs_off);
    int*   cur   = (int*)(w + cur_off);
    int*   perm  = (int*)(w + perm_off);
    float* aggy  = (float*)(w + aggy_off);
    float* aggq  = (float*)(w + aggq_off);
    short* w2up  = (short*)(w + w2_off);
    float* bu2   = (float*)(w + bu2_off);

    ei_sniff_kernel<<<1, 64, 0, stream>>>((const unsigned*)hmat, (const unsigned*)ei, flags);
    hipMemsetAsync(cur, 0, (size_t)N * 4, stream);
    hipMemsetAsync(aggy, 0, (size_t)2 * N * Hdim * 4, stream);  // aggy+aggq contiguous
    ei_hist_kernel<<<256, 256, 0, stream>>>(ei, cur, flags, E);
    ei_scan_kernel<<<1, 1024, 0, stream>>>(cur, rs, N, E);
    ei_scatter_kernel<<<256, 256, 0, stream>>>(ei, cur, perm, flags, E);
    ei_w2up_kernel<<<Hdim + 1, Hdim, 0, stream>>>(W2, Wup, b2, w2up, bu2, flags);
    ei_edge_sorted<<<512, 256, 0, stream>>>(hmat, efeat, shm, ej, perm, (const int*)ei,
                                            W1, b1, Win, bin, Wtp,
                                            aggy, aggq, flags, E / TE);
    ei_node_kernel<<<(N + TE - 1) / TE, 256, 0, stream>>>(
        hmat, heq, w2up, bu2, bup, Wg, bg, rs, aggy, aggq, d_out, flags, N);
}